// Round 1
// baseline (87.900 us; speedup 1.0000x reference)
//
#include <hip/hip_runtime.h>

// Shift op: out[n,c,y,x] = x[n,c, y+dy, x+dx], zero padded.
// c in [0,384). group g = c/42 ; if g>8 (remainder channels) -> g=0.
// dy = g/3 - 1, dx = g%3 - 1.
// Shapes: N=32, C=384, H=64, W=64, float32.

#define N_  32
#define C_  384
#define GS_ 42
#define H_  64
#define W_  64

__global__ __launch_bounds__(256) void shift_kernel(const float* __restrict__ in,
                                                    float* __restrict__ out,
                                                    int total_vec) {
    int idx = blockIdx.x * 256 + threadIdx.x;
    if (idx >= total_vec) return;

    // idx = ((n*C + c)*H + y)*16 + xv   (16 float4 per 64-wide row)
    int xv = idx & 15;
    int t  = idx >> 4;        // (n*C + c)*H + y
    int y  = t & 63;          // H = 64
    int nc = t >> 6;          // n*C + c
    int c  = nc % C_;

    int g = c / GS_;          // 0..9
    if (g > 8) g = 0;         // remainder channels use kernel position (0,0)
    int dy = g / 3 - 1;
    int dx = g - (g / 3) * 3 - 1;

    int sy = y + dy;

    float v[4] = {0.f, 0.f, 0.f, 0.f};
    if ((unsigned)sy < (unsigned)H_) {
        const float* row = in + ((size_t)nc * H_ + sy) * W_;
        int x0 = (xv << 2) + dx;
#pragma unroll
        for (int j = 0; j < 4; ++j) {
            int sx = x0 + j;
            if ((unsigned)sx < (unsigned)W_) v[j] = row[sx];
        }
    }

    float4 o = make_float4(v[0], v[1], v[2], v[3]);
    *reinterpret_cast<float4*>(out + ((size_t)idx << 2)) = o;
}

extern "C" void kernel_launch(void* const* d_in, const int* in_sizes, int n_in,
                              void* d_out, int out_size, void* d_ws, size_t ws_size,
                              hipStream_t stream) {
    const float* x = (const float*)d_in[0];
    float* out = (float*)d_out;

    int total_vec = out_size >> 2;            // 50,331,648 / 4 = 12,582,912
    int blocks = (total_vec + 255) / 256;     // 49,152

    shift_kernel<<<blocks, 256, 0, stream>>>(x, out, total_vec);
}

// Round 3
// 59.958 us; speedup vs baseline: 1.4660x; 1.4660x over previous
//
#include <hip/hip_runtime.h>

// Shift op: out[n,c,y,x] = x[n,c, y+dy, x+dx], zero padded.
// c in [0,384). group g = c/42 ; if g>8 (remainder channels) -> g=0.
// dy = g/3 - 1, dx = g%3 - 1.
// Shapes: N=32, C=384, H=64, W=64, float32.
//
// Strategy: one thread per aligned float4 of the OUTPUT. Load the aligned
// float4 at the same x from the (row-shifted) input, then realign by +/-1
// element in-register via two wave shuffles (neighbor lane holds the
// boundary element). Edge lanes (xv==0 / xv==15) mask the shuffled value
// to zero, which also masks cross-row contamination at 16-lane boundaries.

#define C_  384
#define GS_ 42

typedef float f32x4 __attribute__((ext_vector_type(4)));

__global__ __launch_bounds__(256) void shift_kernel(const float* __restrict__ in,
                                                    float* __restrict__ out) {
    int idx = blockIdx.x * 256 + threadIdx.x;

    // idx = ((n*C + c)*H + y)*16 + xv   (16 float4 per 64-wide row)
    int xv = idx & 15;
    int t  = idx >> 4;        // (n*C + c)*H + y
    int y  = t & 63;          // H = 64
    int nc = t >> 6;          // n*C + c
    int c  = nc % C_;

    int g = c / GS_;          // 0..9
    if (g > 8) g = 0;         // remainder channels use kernel position (0,0)
    int g3 = g / 3;
    int dy = g3 - 1;
    int dx = g - g3 * 3 - 1;

    int sy = y + dy;

    f32x4 l = (f32x4)(0.f);
    if ((unsigned)sy < 64u) {
        // aligned 16B load: row base is 256B-aligned, xv<<2 floats = 16B units
        l = *reinterpret_cast<const f32x4*>(in + (((size_t)nc << 6) + sy) * 64 + (xv << 2));
    }

    // boundary elements from neighbor lanes (all 64 lanes active)
    float up = __shfl_up(l.w, 1);    // prev lane's last element  (for dx=-1)
    float dn = __shfl_down(l.x, 1);  // next lane's first element (for dx=+1)
    if (xv == 0)  up = 0.f;          // left edge of row (also masks cross-row)
    if (xv == 15) dn = 0.f;          // right edge of row

    f32x4 v;
    if (dx < 0)      { v.x = up;  v.y = l.x; v.z = l.y; v.w = l.z; }
    else if (dx > 0) { v.x = l.y; v.y = l.z; v.z = l.w; v.w = dn;  }
    else             v = l;

    // nontemporal store: keep the input resident in Infinity Cache instead
    f32x4* o = reinterpret_cast<f32x4*>(out + ((size_t)idx << 2));
    __builtin_nontemporal_store(v, o);
}

extern "C" void kernel_launch(void* const* d_in, const int* in_sizes, int n_in,
                              void* d_out, int out_size, void* d_ws, size_t ws_size,
                              hipStream_t stream) {
    const float* x = (const float*)d_in[0];
    float* out = (float*)d_out;

    int total_vec = out_size >> 2;            // 50,331,648 / 4 = 12,582,912
    int blocks = total_vec / 256;             // 49,152 (exact)

    shift_kernel<<<blocks, 256, 0, stream>>>(x, out);
}